// Round 18
// baseline (219.093 us; speedup 1.0000x reference)
//
#include <hip/hip_runtime.h>
#include <stdint.h>

#define B_ROWS 32768
#define N_INP 256
#define N_HID 1024
#define NF 256
#define N_IT 100

typedef __attribute__((ext_vector_type(8))) _Float16 f16x8;
typedef __attribute__((ext_vector_type(4))) float f32x4;
typedef __attribute__((ext_vector_type(2))) _Float16 f16x2;
typedef float f32x4a __attribute__((ext_vector_type(4), aligned(4)));
typedef uint32_t u32;

__device__ __forceinline__ ushort f2h(float f) {
  _Float16 h = (_Float16)f;               // v_cvt_f16_f32, RNE
  return *reinterpret_cast<ushort*>(&h);
}

// pack two f32 -> two f16 (RNE) in one u32
__device__ __forceinline__ u32 pkh(float a, float b) {
  _Float16 ha = (_Float16)a, hb = (_Float16)b;
  return (u32)*reinterpret_cast<ushort*>(&ha) |
         ((u32)*reinterpret_cast<ushort*>(&hb) << 16);
}

__device__ __forceinline__ void async_copy16(const void* g, void* l) {
  __builtin_amdgcn_global_load_lds(
      (const __attribute__((address_space(1))) void*)g,
      (__attribute__((address_space(3))) void*)l, 16, 0, 0);
}

__device__ __forceinline__ f16x2 as_h2(u32 x) { return __builtin_bit_cast(f16x2, x); }
__device__ __forceinline__ u32 as_u32(f16x2 x) { return __builtin_bit_cast(u32, x); }
__device__ __forceinline__ f16x2 min2(f16x2 a, f16x2 b) {
  f16x2 r;
  asm("v_pk_min_f16 %0, %1, %2" : "=v"(r) : "v"(a), "v"(b));
  return r;
}

// ---- prepass (small): convert W1/W2 -> f16; extract idx ----
__global__ void prep_kernel(const float* __restrict__ x,
                            const float* __restrict__ W1,
                            const float* __restrict__ W2,
                            ushort* __restrict__ w1h,
                            ushort* __restrict__ w2h,
                            int* __restrict__ idx) {
  if (blockIdx.x < 256) {
    int t = blockIdx.x * 256 + threadIdx.x;          // 65536 threads
    float4 a = reinterpret_cast<const float4*>(W1)[t];
    float4 b = reinterpret_cast<const float4*>(W2)[t];
    reinterpret_cast<ushort4*>(w1h)[t] = make_ushort4(f2h(a.x), f2h(a.y), f2h(a.z), f2h(a.w));
    reinterpret_cast<ushort4*>(w2h)[t] = make_ushort4(f2h(b.x), f2h(b.y), f2h(b.z), f2h(b.w));
  } else {
    int r = (blockIdx.x - 256) * 256 + threadIdx.x;  // 32768 rows
    idx[r] = (int)rintf(x[(size_t)r * 257 + 256] * 255.0f);
  }
}

// ---- MEGA: heterogeneous launch. blocks [0,nG2) = GEMM2+convex+gather on
// chunk k-1 (reads Hr); blocks [nG2,..) = GEMM1 (fused x->f16) on chunk k
// (writes Hw). g2c blocks dispatched first (long pole); gemm1 MFMA work
// co-schedules on the same CUs with g2c's convex VALU phase (m114 overlap).
// Both roles: 1024 thr, 40KB LDS -> 2 blocks/CU, 32 waves/CU.
__global__ __launch_bounds__(1024, 8) void mega(
    const float* __restrict__ Xg1,     // x + k*chunk*257 (role1 input)
    const ushort* __restrict__ w1h,    // [1024][256] f16
    const float* __restrict__ b1,
    ushort* __restrict__ Hw,           // h write buffer (role1 out)
    const ushort* __restrict__ Hr,     // h read buffer (role2 in, chunk k-1)
    const ushort* __restrict__ w2h,    // [256][1024] f16
    const float* __restrict__ b2,
    const int* __restrict__ idxp,      // idx + (k-1)*chunk
    float* __restrict__ outp,          // out + (k-1)*chunk
    int nG2) {
  __shared__ char smraw[40960];
  const int tid = threadIdx.x;
  const int w = tid >> 6, l = tid & 63;

  if ((int)blockIdx.x < nG2) {
    // ================= role2: GEMM2 + convex + gather (R15 proven body) ====
    ushort* smem = (ushort*)smraw;
    const int wm = w >> 2, wn = w & 3;   // 4x4 wave grid
    const int m0r = blockIdx.x * 64;

    f32x4 acc[4];
#pragma unroll
    for (int i = 0; i < 4; ++i) acc[i] = {0.f, 0.f, 0.f, 0.f};

    const int srow = tid >> 2;                        // staging row
    const int scs = (tid & 3) ^ ((srow >> 1) & 3);    // inverse-swizzled src chunk
    const ushort* gA = Hr + (size_t)(m0r + srow) * N_HID + scs * 8;
    const ushort* gB = w2h + (size_t)srow * N_HID + scs * 8;

#define STAGE(kt, buf)                                                  \
  {                                                                     \
    if (tid < 256) async_copy16(gA + (kt) * 32, smem + (buf) * 2048 + tid * 8); \
    async_copy16(gB + (kt) * 32, smem + 4096 + (buf) * 8192 + tid * 8); \
  }

    STAGE(0, 0);
    __syncthreads();

    const int arow = wm * 16 + (l & 15);
    const int brow0 = wn * 64 + (l & 15);
    const int kx = (((l >> 4) ^ ((l >> 1) & 3)) * 8);

    for (int kt = 0; kt < 32; ++kt) {
      const int buf = kt & 1;
      if (kt < 31) STAGE(kt + 1, buf ^ 1);
      f16x8 af = *(const f16x8*)(smem + buf * 2048 + arow * 32 + kx);
#pragma unroll
      for (int ni = 0; ni < 4; ++ni) {
        f16x8 bf = *(const f16x8*)(smem + 4096 + buf * 8192 + (brow0 + ni * 16) * 32 + kx);
        acc[ni] = __builtin_amdgcn_mfma_f32_16x16x32_f16(af, bf, acc[ni], 0, 0, 0);
      }
      __syncthreads();
    }
#undef STAGE

    // epilogue: x_ tile -> f16 in LDS (aliases staging; reads barrier-done)
    {
      const int r0 = wm * 16 + (l >> 4) * 4;
      const int c0 = wn * 64 + (l & 15);
#pragma unroll
      for (int ni = 0; ni < 4; ++ni) {
        const int col = c0 + ni * 16;
        const float bv = b2[col];
#pragma unroll
        for (int r = 0; r < 4; ++r)
          smem[(r0 + r) * 256 + col] = f2h(acc[ni][r] + bv);
      }
    }
    __syncthreads();

    // convex: 16 lanes/row, 16 feats/lane in 8 NAMED u32 words
    const int q = l & 15;
    const int row = w * 4 + (l >> 4);        // 0..63
    u32 w0, w1, w2, w3, w4, w5, w6, w7;
    {
      const uint4* src = reinterpret_cast<const uint4*>(smem + row * 256 + q * 16);
      uint4 v0 = src[0], v1 = src[1];
      w0 = v0.x; w1 = v0.y; w2 = v0.z; w3 = v0.w;
      w4 = v1.x; w5 = v1.y; w6 = v1.z; w7 = v1.w;
    }
    const int ii = idxp[m0r + row];
    const int upIdx = ((l - 1) & 63) * 4;
    const int dnIdx = ((l + 1) & 63) * 4;
    const bool fixP = (q == 0);
    const bool fixN = (q == 15);
    const f16x2 halfc = {(_Float16)0.5f, (_Float16)0.5f};

    u32 P = __builtin_amdgcn_ds_bpermute(upIdx, w7);
    u32 N = __builtin_amdgcn_ds_bpermute(dnIdx, w0);

#define AB(hi, lo) as_h2(__builtin_amdgcn_alignbit((hi), (lo), 16))
#define UPD(wj, sa, sb) wj = as_u32(min2(as_h2(wj), ((sa) + (sb)) * halfc))
#pragma unroll 2
    for (int it = 0; it < N_IT; ++it) {
      const u32 Pf = fixP ? 0x7C000000u : P;   // prev.hi = +inf (feat -1)
      const u32 Nf = fixN ? 0x00007C00u : N;   // next.lo = +inf (feat 256)
      f16x2 s0 = AB(w0, Pf), s1 = AB(w1, w0), s2 = AB(w2, w1), s3 = AB(w3, w2);
      f16x2 s4 = AB(w4, w3), s5 = AB(w5, w4), s6 = AB(w6, w5), s7 = AB(w7, w6);
      f16x2 s8 = AB(Nf, w7);
      UPD(w7, s7, s8);
      UPD(w0, s0, s1);
      P = __builtin_amdgcn_ds_bpermute(upIdx, w7);
      N = __builtin_amdgcn_ds_bpermute(dnIdx, w0);
      UPD(w1, s1, s2); UPD(w2, s2, s3); UPD(w3, s3, s4);
      UPD(w4, s4, s5); UPD(w5, s5, s6); UPD(w6, s6, s7);
    }
#undef AB
#undef UPD

    const int sel = (ii >> 1) & 7;
    u32 a0 = (sel & 4) ? w4 : w0, a1 = (sel & 4) ? w5 : w1;
    u32 a2 = (sel & 4) ? w6 : w2, a3 = (sel & 4) ? w7 : w3;
    u32 b0 = (sel & 2) ? a2 : a0, b1s = (sel & 2) ? a3 : a1;
    u32 c0 = (sel & 1) ? b1s : b0;
    ushort hv = (ii & 1) ? (ushort)(c0 >> 16) : (ushort)(c0 & 0xffffu);
    float v = (float)__builtin_bit_cast(_Float16, hv);
    v = __shfl(v, (l & ~15) | (ii >> 4));
    if (q == 0) outp[m0r + row] = v;

  } else {
    // ================= role1: GEMM1 (fused x->f16), 128x128 tile ===========
    // 16 waves (4x4), BK=32, 8 K-steps. A reg-staged from f32 x (cvt RNE,
    // source chunk-XOR-swizzled, linear ds_write); B via global_load_lds
    // (source-swizzled). Read kx = ((l>>4)^(l&3))*16 bytes for both A and B.
    const int rb = (int)blockIdx.x - nG2;
    const int tm = rb >> 3, tn = rb & 7;
    const float* Xb = Xg1 + (size_t)(tm * 128) * 257;
    const ushort* Bt = w1h + (size_t)(tn * 128) * 256;
    char* As = smraw;            // 2 x 8192 B
    char* Bs = smraw + 16384;    // 2 x 8192 B

    const int sra = tid >> 3;                                   // A row 0..127
    const int ha = tid & 7;                                     // half-chunk
    const int gca = (((ha >> 1) ^ (sra & 3)) << 3) + ((ha & 1) << 2);  // f32 col
    const int srb = tid >> 2;                                   // B row 0..127
    const int cb = (((tid & 3) ^ (srb & 3)) << 3);              // f16 col

    f32x4a av;
    f32x4 acc00 = {0.f, 0.f, 0.f, 0.f}, acc01 = {0.f, 0.f, 0.f, 0.f};
    f32x4 acc10 = {0.f, 0.f, 0.f, 0.f}, acc11 = {0.f, 0.f, 0.f, 0.f};

#define LOADA1(kt) av = *(const f32x4a*)(Xb + (size_t)sra * 257 + (kt) * 32 + gca);
#define WRITEA1(buf)                                                     \
    *(uint2*)(As + (buf) * 8192 + tid * 8) =                             \
        make_uint2(pkh(av.x, av.y), pkh(av.z, av.w));
#define STAGEB1(kt, buf)                                                 \
    if (tid < 512)                                                       \
      async_copy16(Bt + (size_t)srb * 256 + (kt) * 32 + cb,              \
                   Bs + (buf) * 8192 + tid * 16);

    LOADA1(0);
    STAGEB1(0, 0);
    WRITEA1(0);
    __syncthreads();

    const int wmg = w >> 2, wng = w & 3;
    const int lr = l & 15;
    const int kxb = (((l >> 4) ^ (l & 3)) << 4);   // byte offset in row
    const int ra0 = (wmg * 32 + lr) * 64 + kxb;
    const int rbo = (wng * 32 + lr) * 64 + kxb;

    for (int kt = 0; kt < 8; ++kt) {
      const int buf = kt & 1;
      if (kt < 7) { LOADA1(kt + 1); STAGEB1(kt + 1, buf ^ 1); }
      f16x8 a0 = *(const f16x8*)(As + buf * 8192 + ra0);
      f16x8 a1 = *(const f16x8*)(As + buf * 8192 + ra0 + 16 * 64);
      f16x8 bf0 = *(const f16x8*)(Bs + buf * 8192 + rbo);
      f16x8 bf1 = *(const f16x8*)(Bs + buf * 8192 + rbo + 16 * 64);
      acc00 = __builtin_amdgcn_mfma_f32_16x16x32_f16(a0, bf0, acc00, 0, 0, 0);
      acc01 = __builtin_amdgcn_mfma_f32_16x16x32_f16(a0, bf1, acc01, 0, 0, 0);
      acc10 = __builtin_amdgcn_mfma_f32_16x16x32_f16(a1, bf0, acc10, 0, 0, 0);
      acc11 = __builtin_amdgcn_mfma_f32_16x16x32_f16(a1, bf1, acc11, 0, 0, 0);
      if (kt < 7) WRITEA1(buf ^ 1);
      __syncthreads();
    }
#undef LOADA1
#undef WRITEA1
#undef STAGEB1

    const int grow0 = tm * 128 + wmg * 32 + (l >> 4) * 4;
    const int gcol0 = tn * 128 + wng * 32 + lr;
    const float bv0 = b1[gcol0], bv1 = b1[gcol0 + 16];
#pragma unroll
    for (int r = 0; r < 4; ++r) {
      Hw[(size_t)(grow0 + r) * N_HID + gcol0] = f2h(fmaxf(acc00[r] + bv0, 0.f));
      Hw[(size_t)(grow0 + r) * N_HID + gcol0 + 16] = f2h(fmaxf(acc01[r] + bv1, 0.f));
      Hw[(size_t)(grow0 + 16 + r) * N_HID + gcol0] = f2h(fmaxf(acc10[r] + bv0, 0.f));
      Hw[(size_t)(grow0 + 16 + r) * N_HID + gcol0 + 16] = f2h(fmaxf(acc11[r] + bv1, 0.f));
    }
  }
}

extern "C" void kernel_launch(void* const* d_in, const int* in_sizes, int n_in,
                              void* d_out, int out_size, void* d_ws, size_t ws_size,
                              hipStream_t stream) {
  const float* x = (const float*)d_in[0];
  const float* W1 = (const float*)d_in[1];
  const float* b1 = (const float*)d_in[2];
  const float* W2 = (const float*)d_in[3];
  const float* b2 = (const float*)d_in[4];
  float* out = (float*)d_out;

  // workspace layout (16B-aligned)
  char* ws = (char*)d_ws;
  ushort* w1h = (ushort*)ws;                    //    524,288 B
  ushort* w2h = (ushort*)(ws + 524288);         //    524,288 B
  int*    idx = (int*)  (ws + 1048576);         //    131,072 B
  ushort* hbuf = (ushort*)(ws + 1179648);       // 2 x chunk*2048 B (h dbuf)

  const size_t fixed = 1179648;
  int chunk = 2048;
  if (ws_size >= fixed + 2 * (size_t)8192 * 2048) chunk = 8192;
  else if (ws_size >= fixed + 2 * (size_t)4096 * 2048) chunk = 4096;

  prep_kernel<<<384, 256, 0, stream>>>(x, W1, W2, w1h, w2h, idx);

  const int nch = B_ROWS / chunk;
  for (int k = 0; k <= nch; ++k) {
    const int nG1 = (k < nch) ? (chunk / 128) * (N_HID / 128) : 0;
    const int nG2 = (k > 0) ? chunk / 64 : 0;
    const int kw = (k < nch) ? k : 0;        // clamp (unused when nG1==0)
    const int kr = (k > 0) ? (k - 1) : 0;    // clamp (unused when nG2==0)
    ushort* hw = hbuf + (size_t)(kw & 1) * chunk * 1024;
    ushort* hr = hbuf + (size_t)(kr & 1) * chunk * 1024;
    mega<<<nG1 + nG2, 1024, 0, stream>>>(
        x + (size_t)kw * chunk * 257, w1h, b1, hw,
        hr, w2h, b2, idx + (size_t)kr * chunk, out + (size_t)kr * chunk, nG2);
  }
}

// Round 19
// 144.984 us; speedup vs baseline: 1.5112x; 1.5112x over previous
//
#include <hip/hip_runtime.h>
#include <stdint.h>

#define B_ROWS 32768
#define N_INP 256
#define N_HID 1024
#define NF 256
#define N_IT 100

typedef __attribute__((ext_vector_type(8))) _Float16 f16x8;
typedef __attribute__((ext_vector_type(4))) float f32x4;
typedef __attribute__((ext_vector_type(2))) _Float16 f16x2;
typedef float f32x4a __attribute__((ext_vector_type(4), aligned(4)));
typedef uint32_t u32;

__device__ __forceinline__ ushort f2h(float f) {
  _Float16 h = (_Float16)f;               // v_cvt_f16_f32, RNE
  return *reinterpret_cast<ushort*>(&h);
}

// pack two f32 -> two f16 (RNE) in one u32
__device__ __forceinline__ u32 pkh(float a, float b) {
  _Float16 ha = (_Float16)a, hb = (_Float16)b;
  return (u32)*reinterpret_cast<ushort*>(&ha) |
         ((u32)*reinterpret_cast<ushort*>(&hb) << 16);
}

__device__ __forceinline__ void async_copy16(const void* g, void* l) {
  __builtin_amdgcn_global_load_lds(
      (const __attribute__((address_space(1))) void*)g,
      (__attribute__((address_space(3))) void*)l, 16, 0, 0);
}

__device__ __forceinline__ f16x2 as_h2(u32 x) { return __builtin_bit_cast(f16x2, x); }
__device__ __forceinline__ u32 as_u32(f16x2 x) { return __builtin_bit_cast(u32, x); }
__device__ __forceinline__ f16x2 min2(f16x2 a, f16x2 b) {
  f16x2 r;
  asm("v_pk_min_f16 %0, %1, %2" : "=v"(r) : "v"(a), "v"(b));
  return r;
}

// ---- prepass (small): convert W1/W2 -> f16; extract idx ----
__global__ void prep_kernel(const float* __restrict__ x,
                            const float* __restrict__ W1,
                            const float* __restrict__ W2,
                            ushort* __restrict__ w1h,
                            ushort* __restrict__ w2h,
                            int* __restrict__ idx) {
  if (blockIdx.x < 256) {
    int t = blockIdx.x * 256 + threadIdx.x;          // 65536 threads
    float4 a = reinterpret_cast<const float4*>(W1)[t];
    float4 b = reinterpret_cast<const float4*>(W2)[t];
    reinterpret_cast<ushort4*>(w1h)[t] = make_ushort4(f2h(a.x), f2h(a.y), f2h(a.z), f2h(a.w));
    reinterpret_cast<ushort4*>(w2h)[t] = make_ushort4(f2h(b.x), f2h(b.y), f2h(b.z), f2h(b.w));
  } else {
    int r = (blockIdx.x - 256) * 256 + threadIdx.x;  // 32768 rows
    idx[r] = (int)rintf(x[(size_t)r * 257 + 256] * 255.0f);
  }
}

// LDS map (bytes)
#define LDS_A 0          // x-tile / x_ tile: [64][256] f16 = 32768
#define LDS_W1 32768     // W1 chunk [32 hid][256 K] f16 = 16384 (single buf)
#define LDS_W2 49152     // W2 slice [256 out][32 K] f16 = 16384 (single buf)
#define LDS_HP 65536     // h-part dbuf 2 x [64][32] f16 = 2 x 4096

// ---- FULLY FUSED: per 64-row slab: GEMM1 (producer waves 0-7) ->
// h-chunk in LDS -> GEMM2 (consumer waves 8-15, acc in regs) -> convex.
// 32 chunks over hidden dim (32 units each). W1/W2 slices L2-resident,
// single-buffered, staged by all threads with both-sides XOR swizzles.
// No h in HBM. 72KB LDS, 2 blocks/CU.
__global__ __launch_bounds__(1024, 8) void fused_all(
    const float* __restrict__ X,
    const ushort* __restrict__ w1h,    // [1024][256] f16
    const ushort* __restrict__ w2h,    // [256][1024] f16
    const float* __restrict__ b1,
    const float* __restrict__ b2,
    const int* __restrict__ idx,
    float* __restrict__ out) {
  __shared__ char sm[73728];
  ushort* smu = (ushort*)sm;
  const int tid = threadIdx.x;
  const int w = tid >> 6, l = tid & 63;
  const int m0r = blockIdx.x * 64;

  // ---- stage A: x[64][256] f32 -> f16 (RNE), chunk swizzle c^(row&7) ----
  {
    const int row = tid >> 4;
    const int cp = tid & 15;          // k-floats 16cp..16cp+15 -> chunks 2cp, 2cp+1
    const float* xr = X + (size_t)(m0r + row) * 257 + cp * 16;
    f32x4a v0 = *(const f32x4a*)(xr + 0);
    f32x4a v1 = *(const f32x4a*)(xr + 4);
    f32x4a v2 = *(const f32x4a*)(xr + 8);
    f32x4a v3 = *(const f32x4a*)(xr + 12);
    const int c0 = (2 * cp) ^ (row & 7);
    const int c1 = (2 * cp + 1) ^ (row & 7);
    *(uint4*)(sm + LDS_A + row * 512 + c0 * 16) =
        make_uint4(pkh(v0.x, v0.y), pkh(v0.z, v0.w), pkh(v1.x, v1.y), pkh(v1.z, v1.w));
    *(uint4*)(sm + LDS_A + row * 512 + c1 * 16) =
        make_uint4(pkh(v2.x, v2.y), pkh(v2.z, v2.w), pkh(v3.x, v3.y), pkh(v3.z, v3.w));
  }

  // staging sources (inverse-swizzled; dest linear tid*16 per rule #21)
  const int s1h = tid >> 5;                          // W1 dest row 0..31
  const ushort* w1src = w1h + (size_t)s1h * 256 + (((tid & 31) ^ (s1h & 7)) * 8);
  const int s2o = tid >> 2;                          // W2 dest row 0..255
  const ushort* w2src = w2h + (size_t)s2o * 1024 + (((tid & 3) ^ ((s2o >> 1) & 3)) * 8);
#define S1(c) async_copy16(w1src + (size_t)(c) * 8192, sm + LDS_W1 + tid * 16)
#define S2(c) async_copy16(w2src + (c) * 32, sm + LDS_W2 + tid * 16)

  // producer setup (waves 0..7): tile rt=w>>1 (rows), ht=w&1 (hid)
  const int prt = w >> 1, pht = w & 1;
  const int prow = prt * 16 + (l & 15);
  const int phid = pht * 16 + (l & 15);
  const int kq = l >> 4, k7 = l & 7;
  const int hp_csw = ((phid >> 3) & 3);
  // consumer setup (waves 8..15): q8 = w-8; rt2 rows, ot outcols
  const int q8 = w - 8;
  const int rt2 = q8 >> 2, ot = q8 & 3;
  const int kx2 = ((l >> 4) ^ ((l >> 1) & 3)) * 16;
  const int aoff0 = (rt2 * 32 + (l & 15)) * 64 + kx2;

  f32x4 qacc[2][4];
#pragma unroll
  for (int i = 0; i < 2; ++i)
#pragma unroll
    for (int j = 0; j < 4; ++j) qacc[i][j] = {0.f, 0.f, 0.f, 0.f};

  S1(0);
  __syncthreads();   // drains ds_writes (A) + gload_lds (W1 chunk 0)

  float bv_next = b1[phid];   // bias for chunk 0 (producer lanes)

  for (int c = 0; c < 32; ++c) {
    if (w < 8) {
      // ---- producer: h[c] = relu(A @ W1c^T + b1) -> hpart[c&1] ----
      const float bv = bv_next;
      if (c < 31) bv_next = b1[(c + 1) * 32 + phid];   // prefetch under MFMA
      f32x4 pacc = {0.f, 0.f, 0.f, 0.f};
#pragma unroll
      for (int ks = 0; ks < 8; ++ks) {
        const int ch = (ks * 4 + kq) ^ k7;
        f16x8 af = *(const f16x8*)(sm + LDS_A + prow * 512 + ch * 16);
        f16x8 bf = *(const f16x8*)(sm + LDS_W1 + phid * 512 + ch * 16);
        pacc = __builtin_amdgcn_mfma_f32_16x16x32_f16(af, bf, pacc, 0, 0, 0);
      }
      char* hb = sm + LDS_HP + (c & 1) * 4096;
#pragma unroll
      for (int r = 0; r < 4; ++r) {
        const int row = prt * 16 + (l >> 4) * 4 + r;
        ushort hv = f2h(fmaxf(pacc[r] + bv, 0.f));
        *(ushort*)(hb + row * 64 + ((hp_csw ^ ((row >> 1) & 3)) * 16) + (phid & 7) * 2) = hv;
      }
    } else if (c > 0) {
      // ---- consumer: qacc += hpart[c-1] @ W2[c-1]-slice^T ----
      const char* hb = sm + LDS_HP + ((c - 1) & 1) * 4096;
      f16x8 af0 = *(const f16x8*)(hb + aoff0);
      f16x8 af1 = *(const f16x8*)(hb + aoff0 + 16 * 64);
#pragma unroll
      for (int j = 0; j < 4; ++j) {
        const int o = ot * 64 + j * 16 + (l & 15);
        f16x8 bf = *(const f16x8*)(sm + LDS_W2 + o * 64 + kx2);
        qacc[0][j] = __builtin_amdgcn_mfma_f32_16x16x32_f16(af0, bf, qacc[0][j], 0, 0, 0);
        qacc[1][j] = __builtin_amdgcn_mfma_f32_16x16x32_f16(af1, bf, qacc[1][j], 0, 0, 0);
      }
    }
    __syncthreads();            // all reads of W1/W2/hpart done
    if (c < 31) S1(c + 1);
    S2(c);
    __syncthreads();            // staging landed (compiler drains vmcnt)
  }
  // epilogue consumer step: Q(31) (W2 slice 31 staged at loop end)
  if (w >= 8) {
    const char* hb = sm + LDS_HP + (31 & 1) * 4096;
    f16x8 af0 = *(const f16x8*)(hb + aoff0);
    f16x8 af1 = *(const f16x8*)(hb + aoff0 + 16 * 64);
#pragma unroll
    for (int j = 0; j < 4; ++j) {
      const int o = ot * 64 + j * 16 + (l & 15);
      f16x8 bf = *(const f16x8*)(sm + LDS_W2 + o * 64 + kx2);
      qacc[0][j] = __builtin_amdgcn_mfma_f32_16x16x32_f16(af0, bf, qacc[0][j], 0, 0, 0);
      qacc[1][j] = __builtin_amdgcn_mfma_f32_16x16x32_f16(af1, bf, qacc[1][j], 0, 0, 0);
    }
  }
  __syncthreads();

  // x_ tile -> f16 into A region (linear [64][256]; A reads all done)
  if (w >= 8) {
#pragma unroll
    for (int j = 0; j < 4; ++j) {
      const int colb = ot * 64 + j * 16 + (l & 15);
      const float bv = b2[colb];
#pragma unroll
      for (int i = 0; i < 2; ++i)
#pragma unroll
        for (int r = 0; r < 4; ++r) {
          const int row = rt2 * 32 + i * 16 + (l >> 4) * 4 + r;
          smu[row * 256 + colb] = f2h(qacc[i][j][r] + bv);
        }
    }
  }
  __syncthreads();

  // ---- convex: 16 lanes/row, 16 feats/lane in 8 NAMED u32 words ----
  const int q = l & 15;
  const int row = w * 4 + (l >> 4);        // 0..63
  u32 w0, w1, w2, w3, w4, w5, w6, w7;
  {
    const uint4* src = reinterpret_cast<const uint4*>(smu + row * 256 + q * 16);
    uint4 v0 = src[0], v1 = src[1];
    w0 = v0.x; w1 = v0.y; w2 = v0.z; w3 = v0.w;
    w4 = v1.x; w5 = v1.y; w6 = v1.z; w7 = v1.w;
  }
  const int ii = idx[m0r + row];
  const int upIdx = ((l - 1) & 63) * 4;
  const int dnIdx = ((l + 1) & 63) * 4;
  const bool fixP = (q == 0);
  const bool fixN = (q == 15);
  const f16x2 halfc = {(_Float16)0.5f, (_Float16)0.5f};

  u32 P = __builtin_amdgcn_ds_bpermute(upIdx, w7);
  u32 N = __builtin_amdgcn_ds_bpermute(dnIdx, w0);

#define AB(hi, lo) as_h2(__builtin_amdgcn_alignbit((hi), (lo), 16))
#define UPD(wj, sa, sb) wj = as_u32(min2(as_h2(wj), ((sa) + (sb)) * halfc))
#pragma unroll 2
  for (int it = 0; it < N_IT; ++it) {
    const u32 Pf = fixP ? 0x7C000000u : P;   // prev.hi = +inf (feat -1)
    const u32 Nf = fixN ? 0x00007C00u : N;   // next.lo = +inf (feat 256)
    f16x2 s0 = AB(w0, Pf), s1 = AB(w1, w0), s2 = AB(w2, w1), s3 = AB(w3, w2);
    f16x2 s4 = AB(w4, w3), s5 = AB(w5, w4), s6 = AB(w6, w5), s7 = AB(w7, w6);
    f16x2 s8 = AB(Nf, w7);
    UPD(w7, s7, s8);
    UPD(w0, s0, s1);
    P = __builtin_amdgcn_ds_bpermute(upIdx, w7);
    N = __builtin_amdgcn_ds_bpermute(dnIdx, w0);
    UPD(w1, s1, s2); UPD(w2, s2, s3); UPD(w3, s3, s4);
    UPD(w4, s4, s5); UPD(w5, s5, s6); UPD(w6, s6, s7);
  }
#undef AB
#undef UPD

  // gather feature ii: 7-cndmask tree over 8 words, half pick, cvt, shfl
  const int sel = (ii >> 1) & 7;
  u32 a0 = (sel & 4) ? w4 : w0, a1 = (sel & 4) ? w5 : w1;
  u32 a2 = (sel & 4) ? w6 : w2, a3 = (sel & 4) ? w7 : w3;
  u32 b0 = (sel & 2) ? a2 : a0, b1s = (sel & 2) ? a3 : a1;
  u32 c0s = (sel & 1) ? b1s : b0;
  ushort hv = (ii & 1) ? (ushort)(c0s >> 16) : (ushort)(c0s & 0xffffu);
  float v = (float)__builtin_bit_cast(_Float16, hv);
  v = __shfl(v, (l & ~15) | (ii >> 4));
  if (q == 0) out[m0r + row] = v;
#undef S1
#undef S2
}

extern "C" void kernel_launch(void* const* d_in, const int* in_sizes, int n_in,
                              void* d_out, int out_size, void* d_ws, size_t ws_size,
                              hipStream_t stream) {
  const float* x = (const float*)d_in[0];
  const float* W1 = (const float*)d_in[1];
  const float* b1 = (const float*)d_in[2];
  const float* W2 = (const float*)d_in[3];
  const float* b2 = (const float*)d_in[4];
  float* out = (float*)d_out;

  // workspace layout (16B-aligned)
  char* ws = (char*)d_ws;
  ushort* w1h = (ushort*)ws;                    //    524,288 B
  ushort* w2h = (ushort*)(ws + 524288);         //    524,288 B
  int*    idx = (int*)  (ws + 1048576);         //    131,072 B

  prep_kernel<<<384, 256, 0, stream>>>(x, W1, W2, w1h, w2h, idx);
  fused_all<<<B_ROWS / 64, 1024, 0, stream>>>(x, w1h, w2h, b1, b2, idx, out);
}

// Round 20
// 115.525 us; speedup vs baseline: 1.8965x; 1.2550x over previous
//
#include <hip/hip_runtime.h>
#include <stdint.h>

#define B_ROWS 32768
#define N_INP 256
#define N_HID 1024
#define NF 256
#define N_IT 100

typedef __attribute__((ext_vector_type(8))) _Float16 f16x8;
typedef __attribute__((ext_vector_type(4))) float f32x4;
typedef __attribute__((ext_vector_type(2))) _Float16 f16x2;
typedef float f32x4a __attribute__((ext_vector_type(4), aligned(4)));
typedef uint32_t u32;

__device__ __forceinline__ ushort f2h(float f) {
  _Float16 h = (_Float16)f;               // v_cvt_f16_f32, RNE
  return *reinterpret_cast<ushort*>(&h);
}

// pack two f32 -> two f16 (RNE) in one u32
__device__ __forceinline__ u32 pkh(float a, float b) {
  _Float16 ha = (_Float16)a, hb = (_Float16)b;
  return (u32)*reinterpret_cast<ushort*>(&ha) |
         ((u32)*reinterpret_cast<ushort*>(&hb) << 16);
}

__device__ __forceinline__ void async_copy16(const void* g, void* l) {
  __builtin_amdgcn_global_load_lds(
      (const __attribute__((address_space(1))) void*)g,
      (__attribute__((address_space(3))) void*)l, 16, 0, 0);
}

__device__ __forceinline__ f16x2 as_h2(u32 x) { return __builtin_bit_cast(f16x2, x); }
__device__ __forceinline__ u32 as_u32(f16x2 x) { return __builtin_bit_cast(u32, x); }
__device__ __forceinline__ f16x2 min2(f16x2 a, f16x2 b) {
  f16x2 r;
  asm("v_pk_min_f16 %0, %1, %2" : "=v"(r) : "v"(a), "v"(b));
  return r;
}

// ---- prepass (small): convert W1/W2 -> f16; extract idx ----
__global__ void prep_kernel(const float* __restrict__ x,
                            const float* __restrict__ W1,
                            const float* __restrict__ W2,
                            ushort* __restrict__ w1h,
                            ushort* __restrict__ w2h,
                            int* __restrict__ idx) {
  if (blockIdx.x < 256) {
    int t = blockIdx.x * 256 + threadIdx.x;          // 65536 threads
    float4 a = reinterpret_cast<const float4*>(W1)[t];
    float4 b = reinterpret_cast<const float4*>(W2)[t];
    reinterpret_cast<ushort4*>(w1h)[t] = make_ushort4(f2h(a.x), f2h(a.y), f2h(a.z), f2h(a.w));
    reinterpret_cast<ushort4*>(w2h)[t] = make_ushort4(f2h(b.x), f2h(b.y), f2h(b.z), f2h(b.w));
  } else {
    int r = (blockIdx.x - 256) * 256 + threadIdx.x;  // 32768 rows
    idx[r] = (int)rintf(x[(size_t)r * 257 + 256] * 255.0f);
  }
}

// LDS map (bytes)
#define LDS_A 0          // x-tile / x_ tile: [64][256] f16 = 32768
#define LDS_W1 32768     // W1 chunk [32 hid][256 K] f16 = 16384 (single buf)
#define LDS_W2 49152     // W2 slice [256 out][32 K] f16 = 16384 (single buf)
#define LDS_HP 65536     // h-part dbuf 2 x [64][32] f16 = 2 x 4096

// ---- FULLY FUSED: per 64-row slab: GEMM1 (producer waves 0-7) ->
// h-chunk in LDS -> GEMM2 (consumer waves 8-15, acc in regs) -> convex.
// MANUALLY UNSWITCHED by wave role (w<8 is wave-uniform & loop-invariant):
// two loops with IDENTICAL barrier/staging sequences -> no program point
// has producer temps AND consumer qacc live together -> fits the 64-VGPR
// budget of __launch_bounds__(1024,8) (R19 spilled 98MB scratch).
__global__ __launch_bounds__(1024, 8) void fused_all(
    const float* __restrict__ X,
    const ushort* __restrict__ w1h,    // [1024][256] f16
    const ushort* __restrict__ w2h,    // [256][1024] f16
    const float* __restrict__ b1,
    const float* __restrict__ b2,
    const int* __restrict__ idx,
    float* __restrict__ out) {
  __shared__ char sm[73728];
  ushort* smu = (ushort*)sm;
  const int tid = threadIdx.x;
  const int w = tid >> 6, l = tid & 63;
  const int m0r = blockIdx.x * 64;

  // ---- stage A: x[64][256] f32 -> f16 (RNE), chunk swizzle c^(row&7) ----
  {
    const int row = tid >> 4;
    const int cp = tid & 15;
    const float* xr = X + (size_t)(m0r + row) * 257 + cp * 16;
    f32x4a v0 = *(const f32x4a*)(xr + 0);
    f32x4a v1 = *(const f32x4a*)(xr + 4);
    f32x4a v2 = *(const f32x4a*)(xr + 8);
    f32x4a v3 = *(const f32x4a*)(xr + 12);
    const int c0 = (2 * cp) ^ (row & 7);
    const int c1 = (2 * cp + 1) ^ (row & 7);
    *(uint4*)(sm + LDS_A + row * 512 + c0 * 16) =
        make_uint4(pkh(v0.x, v0.y), pkh(v0.z, v0.w), pkh(v1.x, v1.y), pkh(v1.z, v1.w));
    *(uint4*)(sm + LDS_A + row * 512 + c1 * 16) =
        make_uint4(pkh(v2.x, v2.y), pkh(v2.z, v2.w), pkh(v3.x, v3.y), pkh(v3.z, v3.w));
  }

  // staging sources (inverse-swizzled; dest linear tid*16 per rule #21)
  const int s1h = tid >> 5;                          // W1 dest row 0..31
  const ushort* w1src = w1h + (size_t)s1h * 256 + (((tid & 31) ^ (s1h & 7)) * 8);
  const int s2o = tid >> 2;                          // W2 dest row 0..255
  const ushort* w2src = w2h + (size_t)s2o * 1024 + (((tid & 3) ^ ((s2o >> 1) & 3)) * 8);
#define S1(c) async_copy16(w1src + (size_t)(c) * 8192, sm + LDS_W1 + tid * 16)
#define S2(c) async_copy16(w2src + (c) * 32, sm + LDS_W2 + tid * 16)

  S1(0);
  __syncthreads();   // drains ds_writes (A) + gload_lds (W1 chunk 0)

  // consumer geometry (used after the role loops too)
  const int q8 = w - 8;
  const int rt2 = (q8 < 0 ? 0 : q8) >> 2, ot = (q8 < 0 ? 0 : q8) & 3;
  const int kx2 = ((l >> 4) ^ ((l >> 1) & 3)) * 16;
  const int aoff0 = (rt2 * 32 + (l & 15)) * 64 + kx2;

  f32x4 q00 = {0.f, 0.f, 0.f, 0.f}, q01 = {0.f, 0.f, 0.f, 0.f};
  f32x4 q02 = {0.f, 0.f, 0.f, 0.f}, q03 = {0.f, 0.f, 0.f, 0.f};
  f32x4 q10 = {0.f, 0.f, 0.f, 0.f}, q11 = {0.f, 0.f, 0.f, 0.f};
  f32x4 q12 = {0.f, 0.f, 0.f, 0.f}, q13 = {0.f, 0.f, 0.f, 0.f};

  if (w < 8) {
    // =================== PRODUCER loop (waves 0-7) ======================
    const int prt = w >> 1, pht = w & 1;
    const int prow = prt * 16 + (l & 15);
    const int phid = pht * 16 + (l & 15);
    const int kq = l >> 4, k7 = l & 7;
    const int hp_csw = ((phid >> 3) & 3);
    float bv_next = b1[phid];
    for (int c = 0; c < 32; ++c) {
      const float bv = bv_next;
      if (c < 31) bv_next = b1[(c + 1) * 32 + phid];
      f32x4 pacc = {0.f, 0.f, 0.f, 0.f};
#pragma unroll
      for (int ks = 0; ks < 8; ++ks) {
        const int ch = (ks * 4 + kq) ^ k7;
        f16x8 af = *(const f16x8*)(sm + LDS_A + prow * 512 + ch * 16);
        f16x8 bf = *(const f16x8*)(sm + LDS_W1 + phid * 512 + ch * 16);
        pacc = __builtin_amdgcn_mfma_f32_16x16x32_f16(af, bf, pacc, 0, 0, 0);
      }
      char* hb = sm + LDS_HP + (c & 1) * 4096;
#pragma unroll
      for (int r = 0; r < 4; ++r) {
        const int row = prt * 16 + (l >> 4) * 4 + r;
        ushort hv = f2h(fmaxf(pacc[r] + bv, 0.f));
        *(ushort*)(hb + row * 64 + ((hp_csw ^ ((row >> 1) & 3)) * 16) + (phid & 7) * 2) = hv;
      }
      __syncthreads();
      if (c < 31) S1(c + 1);
      S2(c);
      __syncthreads();
    }
  } else {
    // =================== CONSUMER loop (waves 8-15) =====================
    for (int c = 0; c < 32; ++c) {
      if (c > 0) {
        const char* hb = sm + LDS_HP + ((c - 1) & 1) * 4096;
        f16x8 af0 = *(const f16x8*)(hb + aoff0);
        f16x8 af1 = *(const f16x8*)(hb + aoff0 + 16 * 64);
        const int ob = ot * 64 + (l & 15);
        f16x8 bf0 = *(const f16x8*)(sm + LDS_W2 + (ob + 0) * 64 + kx2);
        f16x8 bf1 = *(const f16x8*)(sm + LDS_W2 + (ob + 16) * 64 + kx2);
        f16x8 bf2 = *(const f16x8*)(sm + LDS_W2 + (ob + 32) * 64 + kx2);
        f16x8 bf3 = *(const f16x8*)(sm + LDS_W2 + (ob + 48) * 64 + kx2);
        q00 = __builtin_amdgcn_mfma_f32_16x16x32_f16(af0, bf0, q00, 0, 0, 0);
        q01 = __builtin_amdgcn_mfma_f32_16x16x32_f16(af0, bf1, q01, 0, 0, 0);
        q02 = __builtin_amdgcn_mfma_f32_16x16x32_f16(af0, bf2, q02, 0, 0, 0);
        q03 = __builtin_amdgcn_mfma_f32_16x16x32_f16(af0, bf3, q03, 0, 0, 0);
        q10 = __builtin_amdgcn_mfma_f32_16x16x32_f16(af1, bf0, q10, 0, 0, 0);
        q11 = __builtin_amdgcn_mfma_f32_16x16x32_f16(af1, bf1, q11, 0, 0, 0);
        q12 = __builtin_amdgcn_mfma_f32_16x16x32_f16(af1, bf2, q12, 0, 0, 0);
        q13 = __builtin_amdgcn_mfma_f32_16x16x32_f16(af1, bf3, q13, 0, 0, 0);
      }
      __syncthreads();
      if (c < 31) S1(c + 1);
      S2(c);
      __syncthreads();
    }
    // final consume: h[31] x W2 slice 31 (staged at loop end, barrier'd)
    {
      const char* hb = sm + LDS_HP + 4096;   // 31 & 1
      f16x8 af0 = *(const f16x8*)(hb + aoff0);
      f16x8 af1 = *(const f16x8*)(hb + aoff0 + 16 * 64);
      const int ob = ot * 64 + (l & 15);
      f16x8 bf0 = *(const f16x8*)(sm + LDS_W2 + (ob + 0) * 64 + kx2);
      f16x8 bf1 = *(const f16x8*)(sm + LDS_W2 + (ob + 16) * 64 + kx2);
      f16x8 bf2 = *(const f16x8*)(sm + LDS_W2 + (ob + 32) * 64 + kx2);
      f16x8 bf3 = *(const f16x8*)(sm + LDS_W2 + (ob + 48) * 64 + kx2);
      q00 = __builtin_amdgcn_mfma_f32_16x16x32_f16(af0, bf0, q00, 0, 0, 0);
      q01 = __builtin_amdgcn_mfma_f32_16x16x32_f16(af0, bf1, q01, 0, 0, 0);
      q02 = __builtin_amdgcn_mfma_f32_16x16x32_f16(af0, bf2, q02, 0, 0, 0);
      q03 = __builtin_amdgcn_mfma_f32_16x16x32_f16(af0, bf3, q03, 0, 0, 0);
      q10 = __builtin_amdgcn_mfma_f32_16x16x32_f16(af1, bf0, q10, 0, 0, 0);
      q11 = __builtin_amdgcn_mfma_f32_16x16x32_f16(af1, bf1, q11, 0, 0, 0);
      q12 = __builtin_amdgcn_mfma_f32_16x16x32_f16(af1, bf2, q12, 0, 0, 0);
      q13 = __builtin_amdgcn_mfma_f32_16x16x32_f16(af1, bf3, q13, 0, 0, 0);
    }
  }
  __syncthreads();

  // x_ tile -> f16 into A region (linear [64][256]; A reads all done)
  if (w >= 8) {
    const int colb0 = ot * 64 + (l & 15);
#pragma unroll
    for (int j = 0; j < 4; ++j) {
      const int colb = colb0 + j * 16;
      const float bv = b2[colb];
      const f32x4 qa = (j == 0) ? q00 : (j == 1) ? q01 : (j == 2) ? q02 : q03;
      const f32x4 qb = (j == 0) ? q10 : (j == 1) ? q11 : (j == 2) ? q12 : q13;
#pragma unroll
      for (int r = 0; r < 4; ++r) {
        const int row0 = rt2 * 32 + (l >> 4) * 4 + r;
        smu[row0 * 256 + colb] = f2h(qa[r] + bv);
        smu[(row0 + 16) * 256 + colb] = f2h(qb[r] + bv);
      }
    }
  }
  __syncthreads();

  // ---- convex: 16 lanes/row, 16 feats/lane in 8 NAMED u32 words ----
  const int q = l & 15;
  const int row = w * 4 + (l >> 4);        // 0..63
  u32 w0, w1, w2, w3, w4, w5, w6, w7;
  {
    const uint4* src = reinterpret_cast<const uint4*>(smu + row * 256 + q * 16);
    uint4 v0 = src[0], v1 = src[1];
    w0 = v0.x; w1 = v0.y; w2 = v0.z; w3 = v0.w;
    w4 = v1.x; w5 = v1.y; w6 = v1.z; w7 = v1.w;
  }
  const int ii = idx[m0r + row];
  const int upIdx = ((l - 1) & 63) * 4;
  const int dnIdx = ((l + 1) & 63) * 4;
  const bool fixP = (q == 0);
  const bool fixN = (q == 15);
  const f16x2 halfc = {(_Float16)0.5f, (_Float16)0.5f};

  u32 P = __builtin_amdgcn_ds_bpermute(upIdx, w7);
  u32 N = __builtin_amdgcn_ds_bpermute(dnIdx, w0);

#define AB(hi, lo) as_h2(__builtin_amdgcn_alignbit((hi), (lo), 16))
#define UPD(wj, sa, sb) wj = as_u32(min2(as_h2(wj), ((sa) + (sb)) * halfc))
#pragma unroll 2
  for (int it = 0; it < N_IT; ++it) {
    const u32 Pf = fixP ? 0x7C000000u : P;   // prev.hi = +inf (feat -1)
    const u32 Nf = fixN ? 0x00007C00u : N;   // next.lo = +inf (feat 256)
    f16x2 s0 = AB(w0, Pf), s1 = AB(w1, w0), s2 = AB(w2, w1), s3 = AB(w3, w2);
    f16x2 s4 = AB(w4, w3), s5 = AB(w5, w4), s6 = AB(w6, w5), s7 = AB(w7, w6);
    f16x2 s8 = AB(Nf, w7);
    UPD(w7, s7, s8);
    UPD(w0, s0, s1);
    P = __builtin_amdgcn_ds_bpermute(upIdx, w7);
    N = __builtin_amdgcn_ds_bpermute(dnIdx, w0);
    UPD(w1, s1, s2); UPD(w2, s2, s3); UPD(w3, s3, s4);
    UPD(w4, s4, s5); UPD(w5, s5, s6); UPD(w6, s6, s7);
  }
#undef AB
#undef UPD

  // gather feature ii: 7-cndmask tree over 8 words, half pick, cvt, shfl
  const int sel = (ii >> 1) & 7;
  u32 a0 = (sel & 4) ? w4 : w0, a1 = (sel & 4) ? w5 : w1;
  u32 a2 = (sel & 4) ? w6 : w2, a3 = (sel & 4) ? w7 : w3;
  u32 b0 = (sel & 2) ? a2 : a0, b1s = (sel & 2) ? a3 : a1;
  u32 c0s = (sel & 1) ? b1s : b0;
  ushort hv = (ii & 1) ? (ushort)(c0s >> 16) : (ushort)(c0s & 0xffffu);
  float v = (float)__builtin_bit_cast(_Float16, hv);
  v = __shfl(v, (l & ~15) | (ii >> 4));
  if (q == 0) out[m0r + row] = v;
#undef S1
#undef S2
}

extern "C" void kernel_launch(void* const* d_in, const int* in_sizes, int n_in,
                              void* d_out, int out_size, void* d_ws, size_t ws_size,
                              hipStream_t stream) {
  const float* x = (const float*)d_in[0];
  const float* W1 = (const float*)d_in[1];
  const float* b1 = (const float*)d_in[2];
  const float* W2 = (const float*)d_in[3];
  const float* b2 = (const float*)d_in[4];
  float* out = (float*)d_out;

  // workspace layout (16B-aligned)
  char* ws = (char*)d_ws;
  ushort* w1h = (ushort*)ws;                    //    524,288 B
  ushort* w2h = (ushort*)(ws + 524288);         //    524,288 B
  int*    idx = (int*)  (ws + 1048576);         //    131,072 B

  prep_kernel<<<384, 256, 0, stream>>>(x, W1, W2, w1h, w2h, idx);
  fused_all<<<B_ROWS / 64, 1024, 0, stream>>>(x, w1h, w2h, b1, b2, idx, out);
}

// Round 21
// 109.948 us; speedup vs baseline: 1.9927x; 1.0507x over previous
//
#include <hip/hip_runtime.h>
#include <stdint.h>

#define B_ROWS 32768
#define N_INP 256
#define N_HID 1024
#define NF 256
#define N_IT 100

typedef __attribute__((ext_vector_type(8))) _Float16 f16x8;
typedef __attribute__((ext_vector_type(4))) float f32x4;
typedef __attribute__((ext_vector_type(2))) _Float16 f16x2;
typedef float f32x4a __attribute__((ext_vector_type(4), aligned(4)));
typedef uint32_t u32;

__device__ __forceinline__ ushort f2h(float f) {
  _Float16 h = (_Float16)f;               // v_cvt_f16_f32, RNE
  return *reinterpret_cast<ushort*>(&h);
}

// pack two f32 -> two f16 (RNE) in one u32
__device__ __forceinline__ u32 pkh(float a, float b) {
  _Float16 ha = (_Float16)a, hb = (_Float16)b;
  return (u32)*reinterpret_cast<ushort*>(&ha) |
         ((u32)*reinterpret_cast<ushort*>(&hb) << 16);
}

__device__ __forceinline__ void async_copy16(const void* g, void* l) {
  __builtin_amdgcn_global_load_lds(
      (const __attribute__((address_space(1))) void*)g,
      (__attribute__((address_space(3))) void*)l, 16, 0, 0);
}

__device__ __forceinline__ f16x2 as_h2(u32 x) { return __builtin_bit_cast(f16x2, x); }
__device__ __forceinline__ u32 as_u32(f16x2 x) { return __builtin_bit_cast(u32, x); }
__device__ __forceinline__ f16x2 min2(f16x2 a, f16x2 b) {
  f16x2 r;
  asm("v_pk_min_f16 %0, %1, %2" : "=v"(r) : "v"(a), "v"(b));
  return r;
}

// ---- prepass (small): convert W1/W2 -> f16; extract idx ----
__global__ void prep_kernel(const float* __restrict__ x,
                            const float* __restrict__ W1,
                            const float* __restrict__ W2,
                            ushort* __restrict__ w1h,
                            ushort* __restrict__ w2h,
                            int* __restrict__ idx) {
  if (blockIdx.x < 256) {
    int t = blockIdx.x * 256 + threadIdx.x;          // 65536 threads
    float4 a = reinterpret_cast<const float4*>(W1)[t];
    float4 b = reinterpret_cast<const float4*>(W2)[t];
    reinterpret_cast<ushort4*>(w1h)[t] = make_ushort4(f2h(a.x), f2h(a.y), f2h(a.z), f2h(a.w));
    reinterpret_cast<ushort4*>(w2h)[t] = make_ushort4(f2h(b.x), f2h(b.y), f2h(b.z), f2h(b.w));
  } else {
    int r = (blockIdx.x - 256) * 256 + threadIdx.x;  // 32768 rows
    idx[r] = (int)rintf(x[(size_t)r * 257 + 256] * 255.0f);
  }
}

// LDS map (bytes)
#define LDS_A 0          // x-tile / x_ tile: [64][256] f16 = 32768
#define LDS_W1 32768     // W1 chunk [32 hid][256 K] f16 = 16384 (single buf)
#define LDS_W2 49152     // W2 slice [256 out][32 K] f16 = 16384 (single buf)
#define LDS_HP 65536     // h-part dbuf 2 x [64][32] f16 = 2 x 4096

// ---- FULLY FUSED: per 64-row slab: GEMM1 (producer waves 0-7) ->
// h-chunk in LDS -> GEMM2 (consumer waves 8-15, acc in regs) -> convex.
// Unswitched by wave role. R21: consumer uses ROLLING bf (one W2 fragment
// live at a time) + explicit named-register writeback -> peak live set
// ~52 VGPR < the 64-VGPR cap of launch_bounds(1024,8) -> no scratch spill
// (R20 spilled 22MB: all 4 bf live + ternary select chains).
__global__ __launch_bounds__(1024, 8) void fused_all(
    const float* __restrict__ X,
    const ushort* __restrict__ w1h,    // [1024][256] f16
    const ushort* __restrict__ w2h,    // [256][1024] f16
    const float* __restrict__ b1,
    const float* __restrict__ b2,
    const int* __restrict__ idx,
    float* __restrict__ out) {
  __shared__ char sm[73728];
  ushort* smu = (ushort*)sm;
  const int tid = threadIdx.x;
  const int w = tid >> 6, l = tid & 63;
  const int m0r = blockIdx.x * 64;

  // ---- stage A: x[64][256] f32 -> f16 (RNE), chunk swizzle c^(row&7) ----
  {
    const int row = tid >> 4;
    const int cp = tid & 15;
    const float* xr = X + (size_t)(m0r + row) * 257 + cp * 16;
    f32x4a v0 = *(const f32x4a*)(xr + 0);
    f32x4a v1 = *(const f32x4a*)(xr + 4);
    f32x4a v2 = *(const f32x4a*)(xr + 8);
    f32x4a v3 = *(const f32x4a*)(xr + 12);
    const int c0 = (2 * cp) ^ (row & 7);
    const int c1 = (2 * cp + 1) ^ (row & 7);
    *(uint4*)(sm + LDS_A + row * 512 + c0 * 16) =
        make_uint4(pkh(v0.x, v0.y), pkh(v0.z, v0.w), pkh(v1.x, v1.y), pkh(v1.z, v1.w));
    *(uint4*)(sm + LDS_A + row * 512 + c1 * 16) =
        make_uint4(pkh(v2.x, v2.y), pkh(v2.z, v2.w), pkh(v3.x, v3.y), pkh(v3.z, v3.w));
  }

  // staging sources (inverse-swizzled; dest linear tid*16 per rule #21)
  const int s1h = tid >> 5;                          // W1 dest row 0..31
  const ushort* w1src = w1h + (size_t)s1h * 256 + (((tid & 31) ^ (s1h & 7)) * 8);
  const int s2o = tid >> 2;                          // W2 dest row 0..255
  const ushort* w2src = w2h + (size_t)s2o * 1024 + (((tid & 3) ^ ((s2o >> 1) & 3)) * 8);
#define S1(c) async_copy16(w1src + (size_t)(c) * 8192, sm + LDS_W1 + tid * 16)
#define S2(c) async_copy16(w2src + (c) * 32, sm + LDS_W2 + tid * 16)

  S1(0);
  __syncthreads();   // drains ds_writes (A) + gload_lds (W1 chunk 0)

  // consumer geometry (used after the role loops too)
  const int q8 = w - 8;
  const int rt2 = (q8 < 0 ? 0 : q8) >> 2, ot = (q8 < 0 ? 0 : q8) & 3;
  const int kx2 = ((l >> 4) ^ ((l >> 1) & 3)) * 16;
  const int aoff0 = (rt2 * 32 + (l & 15)) * 64 + kx2;
  const int ob = ot * 64 + (l & 15);

  f32x4 q00 = {0.f, 0.f, 0.f, 0.f}, q01 = {0.f, 0.f, 0.f, 0.f};
  f32x4 q02 = {0.f, 0.f, 0.f, 0.f}, q03 = {0.f, 0.f, 0.f, 0.f};
  f32x4 q10 = {0.f, 0.f, 0.f, 0.f}, q11 = {0.f, 0.f, 0.f, 0.f};
  f32x4 q12 = {0.f, 0.f, 0.f, 0.f}, q13 = {0.f, 0.f, 0.f, 0.f};

  // consumer inner body: rolling bf -- ONE W2 fragment live at a time.
  // Per-accumulator MFMA sequence identical to R20 (one mfma per chunk).
#define CONSUME(hbp)                                                         \
  {                                                                          \
    f16x8 af0 = *(const f16x8*)((hbp) + aoff0);                              \
    f16x8 af1 = *(const f16x8*)((hbp) + aoff0 + 16 * 64);                    \
    f16x8 bf;                                                                \
    bf = *(const f16x8*)(sm + LDS_W2 + (ob + 0) * 64 + kx2);                 \
    q00 = __builtin_amdgcn_mfma_f32_16x16x32_f16(af0, bf, q00, 0, 0, 0);     \
    q10 = __builtin_amdgcn_mfma_f32_16x16x32_f16(af1, bf, q10, 0, 0, 0);     \
    bf = *(const f16x8*)(sm + LDS_W2 + (ob + 16) * 64 + kx2);                \
    q01 = __builtin_amdgcn_mfma_f32_16x16x32_f16(af0, bf, q01, 0, 0, 0);     \
    q11 = __builtin_amdgcn_mfma_f32_16x16x32_f16(af1, bf, q11, 0, 0, 0);     \
    bf = *(const f16x8*)(sm + LDS_W2 + (ob + 32) * 64 + kx2);                \
    q02 = __builtin_amdgcn_mfma_f32_16x16x32_f16(af0, bf, q02, 0, 0, 0);     \
    q12 = __builtin_amdgcn_mfma_f32_16x16x32_f16(af1, bf, q12, 0, 0, 0);     \
    bf = *(const f16x8*)(sm + LDS_W2 + (ob + 48) * 64 + kx2);                \
    q03 = __builtin_amdgcn_mfma_f32_16x16x32_f16(af0, bf, q03, 0, 0, 0);     \
    q13 = __builtin_amdgcn_mfma_f32_16x16x32_f16(af1, bf, q13, 0, 0, 0);     \
  }

  if (w < 8) {
    // =================== PRODUCER loop (waves 0-7) ======================
    const int prt = w >> 1, pht = w & 1;
    const int prow = prt * 16 + (l & 15);
    const int phid = pht * 16 + (l & 15);
    const int kq = l >> 4, k7 = l & 7;
    const int hp_csw = ((phid >> 3) & 3);
    float bv_next = b1[phid];
    for (int c = 0; c < 32; ++c) {
      const float bv = bv_next;
      if (c < 31) bv_next = b1[(c + 1) * 32 + phid];
      f32x4 pacc = {0.f, 0.f, 0.f, 0.f};
#pragma unroll
      for (int ks = 0; ks < 8; ++ks) {
        const int ch = (ks * 4 + kq) ^ k7;
        f16x8 af = *(const f16x8*)(sm + LDS_A + prow * 512 + ch * 16);
        f16x8 bf = *(const f16x8*)(sm + LDS_W1 + phid * 512 + ch * 16);
        pacc = __builtin_amdgcn_mfma_f32_16x16x32_f16(af, bf, pacc, 0, 0, 0);
      }
      char* hb = sm + LDS_HP + (c & 1) * 4096;
#pragma unroll
      for (int r = 0; r < 4; ++r) {
        const int row = prt * 16 + (l >> 4) * 4 + r;
        ushort hv = f2h(fmaxf(pacc[r] + bv, 0.f));
        *(ushort*)(hb + row * 64 + ((hp_csw ^ ((row >> 1) & 3)) * 16) + (phid & 7) * 2) = hv;
      }
      __syncthreads();
      if (c < 31) S1(c + 1);
      S2(c);
      __syncthreads();
    }
  } else {
    // =================== CONSUMER loop (waves 8-15) =====================
    for (int c = 0; c < 32; ++c) {
      if (c > 0) {
        const char* hb = sm + LDS_HP + ((c - 1) & 1) * 4096;
        CONSUME(hb);
      }
      __syncthreads();
      if (c < 31) S1(c + 1);
      S2(c);
      __syncthreads();
    }
    // final consume: h[31] x W2 slice 31 (staged at loop end, barrier'd)
    {
      const char* hb = sm + LDS_HP + 4096;   // 31 & 1
      CONSUME(hb);
    }
  }
#undef CONSUME
  __syncthreads();

  // x_ tile -> f16 into A region (linear [64][256]; A reads all done).
  // Explicit named-register writeback (no select chains -> no copies).
  if (w >= 8) {
    const int colb0 = ot * 64 + (l & 15);
    const int row0 = rt2 * 32 + (l >> 4) * 4;
#define WB(qa, qb, jj)                                                       \
    {                                                                        \
      const int colb = colb0 + (jj) * 16;                                    \
      const float bv = b2[colb];                                             \
      _Pragma("unroll") for (int r = 0; r < 4; ++r) {                        \
        smu[(row0 + r) * 256 + colb] = f2h(qa[r] + bv);                      \
        smu[(row0 + 16 + r) * 256 + colb] = f2h(qb[r] + bv);                 \
      }                                                                      \
    }
    WB(q00, q10, 0);
    WB(q01, q11, 1);
    WB(q02, q12, 2);
    WB(q03, q13, 3);
#undef WB
  }
  __syncthreads();

  // ---- convex: 16 lanes/row, 16 feats/lane in 8 NAMED u32 words ----
  const int q = l & 15;
  const int row = w * 4 + (l >> 4);        // 0..63
  u32 w0, w1, w2, w3, w4, w5, w6, w7;
  {
    const uint4* src = reinterpret_cast<const uint4*>(smu + row * 256 + q * 16);
    uint4 v0 = src[0], v1 = src[1];
    w0 = v0.x; w1 = v0.y; w2 = v0.z; w3 = v0.w;
    w4 = v1.x; w5 = v1.y; w6 = v1.z; w7 = v1.w;
  }
  const int ii = idx[m0r + row];
  const int upIdx = ((l - 1) & 63) * 4;
  const int dnIdx = ((l + 1) & 63) * 4;
  const bool fixP = (q == 0);
  const bool fixN = (q == 15);
  const f16x2 halfc = {(_Float16)0.5f, (_Float16)0.5f};

  u32 P = __builtin_amdgcn_ds_bpermute(upIdx, w7);
  u32 N = __builtin_amdgcn_ds_bpermute(dnIdx, w0);

#define AB(hi, lo) as_h2(__builtin_amdgcn_alignbit((hi), (lo), 16))
#define UPD(wj, sa, sb) wj = as_u32(min2(as_h2(wj), ((sa) + (sb)) * halfc))
#pragma unroll 2
  for (int it = 0; it < N_IT; ++it) {
    const u32 Pf = fixP ? 0x7C000000u : P;   // prev.hi = +inf (feat -1)
    const u32 Nf = fixN ? 0x00007C00u : N;   // next.lo = +inf (feat 256)
    f16x2 s0 = AB(w0, Pf), s1 = AB(w1, w0), s2 = AB(w2, w1), s3 = AB(w3, w2);
    f16x2 s4 = AB(w4, w3), s5 = AB(w5, w4), s6 = AB(w6, w5), s7 = AB(w7, w6);
    f16x2 s8 = AB(Nf, w7);
    UPD(w7, s7, s8);
    UPD(w0, s0, s1);
    P = __builtin_amdgcn_ds_bpermute(upIdx, w7);
    N = __builtin_amdgcn_ds_bpermute(dnIdx, w0);
    UPD(w1, s1, s2); UPD(w2, s2, s3); UPD(w3, s3, s4);
    UPD(w4, s4, s5); UPD(w5, s5, s6); UPD(w6, s6, s7);
  }
#undef AB
#undef UPD

  // gather feature ii: 7-cndmask tree over 8 words, half pick, cvt, shfl
  const int sel = (ii >> 1) & 7;
  u32 a0 = (sel & 4) ? w4 : w0, a1 = (sel & 4) ? w5 : w1;
  u32 a2 = (sel & 4) ? w6 : w2, a3 = (sel & 4) ? w7 : w3;
  u32 b0 = (sel & 2) ? a2 : a0, b1s = (sel & 2) ? a3 : a1;
  u32 c0s = (sel & 1) ? b1s : b0;
  ushort hv = (ii & 1) ? (ushort)(c0s >> 16) : (ushort)(c0s & 0xffffu);
  float v = (float)__builtin_bit_cast(_Float16, hv);
  v = __shfl(v, (l & ~15) | (ii >> 4));
  if (q == 0) out[m0r + row] = v;
#undef S1
#undef S2
}

extern "C" void kernel_launch(void* const* d_in, const int* in_sizes, int n_in,
                              void* d_out, int out_size, void* d_ws, size_t ws_size,
                              hipStream_t stream) {
  const float* x = (const float*)d_in[0];
  const float* W1 = (const float*)d_in[1];
  const float* b1 = (const float*)d_in[2];
  const float* W2 = (const float*)d_in[3];
  const float* b2 = (const float*)d_in[4];
  float* out = (float*)d_out;

  // workspace layout (16B-aligned)
  char* ws = (char*)d_ws;
  ushort* w1h = (ushort*)ws;                    //    524,288 B
  ushort* w2h = (ushort*)(ws + 524288);         //    524,288 B
  int*    idx = (int*)  (ws + 1048576);         //    131,072 B

  prep_kernel<<<384, 256, 0, stream>>>(x, W1, W2, w1h, w2h, idx);
  fused_all<<<B_ROWS / 64, 1024, 0, stream>>>(x, w1h, w2h, b1, b2, idx, out);
}